// Round 4
// baseline (488.592 us; speedup 1.0000x reference)
//
#include <hip/hip_runtime.h>
#include <cstdint>

#define N_NODES 50000
#define N_EDGES 600000
#define DCH     128
#define LN_EPS  1e-5f
#define SCAN_BLOCKS 196   // ceil(50000/256)

// ---------------- edge dtype detection (int32 vs raw int64) ----------------
__global__ void detect_k(const int* __restrict__ ei, int* __restrict__ flag) {
    __shared__ int bad;
    if (threadIdx.x == 0) bad = 0;
    __syncthreads();
    const long long* e64 = (const long long*)ei;
    long long v = e64[threadIdx.x];
    long long w = e64[300000 + threadIdx.x];
    if (v < 0 || v >= N_NODES || w < 0 || w >= N_NODES) bad = 1;
    __syncthreads();
    if (threadIdx.x == 0) *flag = (bad == 0) ? 1 : 0;   // 1 => int64 layout
}

__device__ inline int edge_at(const int* __restrict__ ei, int is64, long long idx) {
    long long v = is64 ? ((const long long*)ei)[idx] : (long long)ei[idx];
    if (v < 0) v = 0;
    if (v >= N_NODES) v = N_NODES - 1;
    return (int)v;
}

// ---------------- CSR construction ----------------

__global__ void count_k(const int* __restrict__ ei, const int* __restrict__ flag,
                        int* __restrict__ cnt) {
    int e = blockIdx.x * 256 + threadIdx.x;
    if (e < N_EDGES) {
        int d = edge_at(ei, *flag, (long long)N_EDGES + e);
        atomicAdd(&cnt[d], 1);
    }
}

__global__ void scan_block_k(const int* __restrict__ cnt, int* __restrict__ row_start,
                             int* __restrict__ bsums) {
    __shared__ int sm[256];
    int t = threadIdx.x;
    int i = blockIdx.x * 256 + t;
    int v = (i < N_NODES) ? cnt[i] : 0;
    sm[t] = v; __syncthreads();
    #pragma unroll
    for (int off = 1; off < 256; off <<= 1) {
        int x = (t >= off) ? sm[t - off] : 0;
        __syncthreads();
        sm[t] += x;
        __syncthreads();
    }
    if (i < N_NODES) row_start[i] = sm[t] - v;
    if (t == 255)    bsums[blockIdx.x] = sm[255];
}

__global__ void scan_top_k(int* __restrict__ bsums) {
    __shared__ int sm[256];
    int t = threadIdx.x;
    int v = (t < SCAN_BLOCKS) ? bsums[t] : 0;
    sm[t] = v; __syncthreads();
    #pragma unroll
    for (int off = 1; off < 256; off <<= 1) {
        int x = (t >= off) ? sm[t - off] : 0;
        __syncthreads();
        sm[t] += x;
        __syncthreads();
    }
    if (t < SCAN_BLOCKS) bsums[t] = sm[t] - v;
}

__global__ void finalize_k(const int* __restrict__ cnt, int* __restrict__ row_start,
                           int* __restrict__ cursor, const int* __restrict__ bsums,
                           float* __restrict__ dinv2, float* __restrict__ dinv1) {
    int i = blockIdx.x * 256 + threadIdx.x;
    if (i >= N_NODES) return;
    int rs = row_start[i] + bsums[blockIdx.x];
    row_start[i] = rs;
    cursor[i]    = rs;
    float c = (float)cnt[i];
    dinv2[i] = rsqrtf(c + 3.0f);   // fill=2: cnt + 1 + 2
    dinv1[i] = rsqrtf(c + 2.0f);   // fill=1: cnt + 1 + 1
}

__global__ void fill_k(const int* __restrict__ ei, const int* __restrict__ flag,
                       int* __restrict__ cursor, int* __restrict__ csr) {
    int e = blockIdx.x * 256 + threadIdx.x;
    if (e >= N_EDGES) return;
    int is64 = *flag;
    int s = edge_at(ei, is64, e);
    int d = edge_at(ei, is64, (long long)N_EDGES + e);
    int pos = atomicAdd(&cursor[d], 1);
    csr[pos] = s;
}

// ------- Aggregation (f32): agg[d] = di[d]*sum_s(di[s]*h[s]) + di[d]^2*(1+fill)*h[d]

__global__ __launch_bounds__(256) void agg_k(
        const float* __restrict__ h, float* __restrict__ out,
        const int* __restrict__ row_start, const int* __restrict__ cnt,
        const int* __restrict__ csr, const float* __restrict__ dinv, float fillp1) {
    int lane = threadIdx.x & 63;
    int node = blockIdx.x * 4 + (threadIdx.x >> 6);      // 50000/4 = 12500 exact
    float di = dinv[node];
    int rs = row_start[node];
    int c  = cnt[node];
    float a0 = 0.f, a1 = 0.f;
    const float* hp = h + lane * 2;                      // channels 2*lane, 2*lane+1
    for (int i = 0; i < c; i++) {
        int s = csr[rs + i];
        float w = dinv[s];
        float2 u = *(const float2*)(hp + (size_t)s * DCH);
        a0 += w * u.x;
        a1 += w * u.y;
    }
    float2 u = *(const float2*)(hp + (size_t)node * DCH);
    float dd = di * di * fillp1;
    a0 = di * a0 + dd * u.x;
    a1 = di * a1 + dd * u.y;
    float2 r; r.x = a0; r.y = a1;
    *(float2*)(out + (size_t)node * DCH + lane * 2) = r;
}

// ---------------- f32 register-tiled GEMM + fused epilogue ----------------
// Block: 256 threads -> 64 nodes x 128 channels. Thread (cg=t&15, ng=t>>4)
// computes nodes ng*4..+3, channels cg*8..+7. A-tile in LDS (row pad 132 ->
// 2-way banking = free). W read from global as float4 (L2-served).
// MODE 0: out = relu(LN(A@W + bias)*gamma + beta)
// MODE 1: out = A@W + bias + resid

template<int MODE>
__global__ __launch_bounds__(256) void gemm_k(
        const float* __restrict__ A,
        const float* __restrict__ W,       // [k][n] row-major 128x128
        const float* __restrict__ bias,
        const float* __restrict__ gamma,
        const float* __restrict__ beta,
        const float* __restrict__ resid,
        float* __restrict__ out) {
    __shared__ float Al[64][132];
    int t  = threadIdx.x;
    int n0 = blockIdx.x * 64;
    #pragma unroll
    for (int j = 0; j < 32; j++) {
        int idx = t + 256 * j;            // 0..8191
        int r = idx >> 7, k = idx & 127;
        int gr = n0 + r; if (gr >= N_NODES) gr = N_NODES - 1;
        Al[r][k] = A[(size_t)gr * DCH + k];
    }
    __syncthreads();

    int cg = t & 15, ng = t >> 4;
    int c0 = cg * 8, nl = ng * 4;

    float acc[4][8];
    #pragma unroll
    for (int r = 0; r < 4; r++)
        #pragma unroll
        for (int j = 0; j < 8; j++) acc[r][j] = 0.f;

    #pragma unroll 4
    for (int k = 0; k < 128; k++) {
        float4 w0 = *(const float4*)(W + k * DCH + c0);
        float4 w1 = *(const float4*)(W + k * DCH + c0 + 4);
        float wv[8] = {w0.x, w0.y, w0.z, w0.w, w1.x, w1.y, w1.z, w1.w};
        float av[4] = {Al[nl + 0][k], Al[nl + 1][k], Al[nl + 2][k], Al[nl + 3][k]};
        #pragma unroll
        for (int r = 0; r < 4; r++)
            #pragma unroll
            for (int j = 0; j < 8; j++)
                acc[r][j] = fmaf(av[r], wv[j], acc[r][j]);
    }

    float bv[8];
    #pragma unroll
    for (int j = 0; j < 8; j++) bv[j] = bias[c0 + j];

    if (MODE == 0) {
        float gv[8], bev[8];
        #pragma unroll
        for (int j = 0; j < 8; j++) { gv[j] = gamma[c0 + j]; bev[j] = beta[c0 + j]; }
        #pragma unroll
        for (int r = 0; r < 4; r++)
            #pragma unroll
            for (int j = 0; j < 8; j++) acc[r][j] += bv[j];
        // LN per node row: the 16 threads of group ng are 16 contiguous lanes
        // of one wave -> width-16 shfl_xor reduces over all 128 channels.
        #pragma unroll
        for (int r = 0; r < 4; r++) {
            float s = 0.f, qs = 0.f;
            #pragma unroll
            for (int j = 0; j < 8; j++) { float v = acc[r][j]; s += v; qs += v * v; }
            #pragma unroll
            for (int m = 1; m < 16; m <<= 1) {
                s  += __shfl_xor(s,  m, 16);
                qs += __shfl_xor(qs, m, 16);
            }
            float mean = s * (1.f / 128.f);
            float var  = fmaxf(qs * (1.f / 128.f) - mean * mean, 0.f);
            float rstd = rsqrtf(var + LN_EPS);
            int gr = n0 + nl + r;
            if (gr < N_NODES) {
                float4 o0, o1;
                o0.x = fmaxf((acc[r][0] - mean) * rstd * gv[0] + bev[0], 0.f);
                o0.y = fmaxf((acc[r][1] - mean) * rstd * gv[1] + bev[1], 0.f);
                o0.z = fmaxf((acc[r][2] - mean) * rstd * gv[2] + bev[2], 0.f);
                o0.w = fmaxf((acc[r][3] - mean) * rstd * gv[3] + bev[3], 0.f);
                o1.x = fmaxf((acc[r][4] - mean) * rstd * gv[4] + bev[4], 0.f);
                o1.y = fmaxf((acc[r][5] - mean) * rstd * gv[5] + bev[5], 0.f);
                o1.z = fmaxf((acc[r][6] - mean) * rstd * gv[6] + bev[6], 0.f);
                o1.w = fmaxf((acc[r][7] - mean) * rstd * gv[7] + bev[7], 0.f);
                *(float4*)(out + (size_t)gr * DCH + c0)     = o0;
                *(float4*)(out + (size_t)gr * DCH + c0 + 4) = o1;
            }
        }
    } else {
        #pragma unroll
        for (int r = 0; r < 4; r++) {
            int gr = n0 + nl + r;
            if (gr < N_NODES) {
                float4 r0 = *(const float4*)(resid + (size_t)gr * DCH + c0);
                float4 r1 = *(const float4*)(resid + (size_t)gr * DCH + c0 + 4);
                float4 o0, o1;
                o0.x = acc[r][0] + bv[0] + r0.x;
                o0.y = acc[r][1] + bv[1] + r0.y;
                o0.z = acc[r][2] + bv[2] + r0.z;
                o0.w = acc[r][3] + bv[3] + r0.w;
                o1.x = acc[r][4] + bv[4] + r1.x;
                o1.y = acc[r][5] + bv[5] + r1.y;
                o1.z = acc[r][6] + bv[6] + r1.z;
                o1.w = acc[r][7] + bv[7] + r1.w;
                *(float4*)(out + (size_t)gr * DCH + c0)     = o0;
                *(float4*)(out + (size_t)gr * DCH + c0 + 4) = o1;
            }
        }
    }
}

// ---------------- launcher ----------------

extern "C" void kernel_launch(void* const* d_in, const int* in_sizes, int n_in,
                              void* d_out, int out_size, void* d_ws, size_t ws_size,
                              hipStream_t stream) {
    const float* x   = (const float*)d_in[0];
    const int*   ei  = (const int*)d_in[1];
    const float* W1  = (const float*)d_in[2];
    const float* b1  = (const float*)d_in[3];
    const float* g1  = (const float*)d_in[4];
    const float* be1 = (const float*)d_in[5];
    const float* W2  = (const float*)d_in[6];
    const float* b2  = (const float*)d_in[7];
    const float* g2  = (const float*)d_in[8];
    const float* be2 = (const float*)d_in[9];
    const float* W3  = (const float*)d_in[10];
    const float* b3  = (const float*)d_in[11];
    float* out = (float*)d_out;

    char* p = (char*)d_ws;
    auto alloc = [&](size_t bytes) -> void* {
        void* r = (void*)p; p += (bytes + 255) & ~(size_t)255; return r;
    };
    int*   eflag     = (int*)  alloc(256);
    int*   cnt       = (int*)  alloc((size_t)N_NODES * 4);
    int*   row_start = (int*)  alloc((size_t)N_NODES * 4);
    int*   cursor    = (int*)  alloc((size_t)N_NODES * 4);
    int*   bsums     = (int*)  alloc(256 * 4);
    float* dinv2     = (float*)alloc((size_t)N_NODES * 4);
    float* dinv1     = (float*)alloc((size_t)N_NODES * 4);
    int*   csr       = (int*)  alloc((size_t)N_EDGES * 4);
    float* aggb      = (float*)alloc((size_t)N_NODES * DCH * 4);
    // d_out (f32, N*D) doubles as the inter-layer h buffer (stream-ordered).
    float* hbuf = out;

    hipMemsetAsync(cnt, 0, (size_t)N_NODES * 4, stream);
    detect_k<<<1, 256, 0, stream>>>(ei, eflag);
    count_k<<<(N_EDGES + 255) / 256, 256, 0, stream>>>(ei, eflag, cnt);
    scan_block_k<<<SCAN_BLOCKS, 256, 0, stream>>>(cnt, row_start, bsums);
    scan_top_k<<<1, 256, 0, stream>>>(bsums);
    finalize_k<<<SCAN_BLOCKS, 256, 0, stream>>>(cnt, row_start, cursor, bsums, dinv2, dinv1);
    fill_k<<<(N_EDGES + 255) / 256, 256, 0, stream>>>(ei, eflag, cursor, csr);

    const int G_BLOCKS = (N_NODES + 63) / 64;   // 782

    // layer 1: agg(x, fill=2) -> @W1 + b1 -> LN*g1+be1 -> relu
    agg_k<<<N_NODES / 4, 256, 0, stream>>>(x, aggb, row_start, cnt, csr, dinv2, 3.0f);
    gemm_k<0><<<G_BLOCKS, 256, 0, stream>>>(aggb, W1, b1, g1, be1, nullptr, hbuf);
    // layer 2
    agg_k<<<N_NODES / 4, 256, 0, stream>>>(hbuf, aggb, row_start, cnt, csr, dinv2, 3.0f);
    gemm_k<0><<<G_BLOCKS, 256, 0, stream>>>(aggb, W2, b2, g2, be2, nullptr, hbuf);
    // layer 3: fill=1, + b3 + residual x
    agg_k<<<N_NODES / 4, 256, 0, stream>>>(hbuf, aggb, row_start, cnt, csr, dinv1, 2.0f);
    gemm_k<1><<<G_BLOCKS, 256, 0, stream>>>(aggb, W3, b3, nullptr, nullptr, x, out);
}

// Round 5
// 340.323 us; speedup vs baseline: 1.4357x; 1.4357x over previous
//
#include <hip/hip_runtime.h>
#include <hip/hip_bf16.h>
#include <cstdint>

#define N_NODES 50000
#define N_EDGES 600000
#define DCH     128
#define LN_EPS  1e-5f
#define SCAN_BLOCKS 196   // ceil(50000/256)

typedef __attribute__((ext_vector_type(8))) __bf16 bf16x8;
typedef __attribute__((ext_vector_type(4))) float  f32x4;

__device__ inline unsigned short f2bf(float f) {
    unsigned int b; __builtin_memcpy(&b, &f, 4);
    b = b + 0x7fffu + ((b >> 16) & 1u);   // round-to-nearest-even
    return (unsigned short)(b >> 16);
}
__device__ inline float bf_lo(unsigned int u) {   // low bf16 of packed pair
    unsigned int t = u << 16; float f; __builtin_memcpy(&f, &t, 4); return f;
}
__device__ inline float bf_hi(unsigned int u) {   // high bf16 of packed pair
    unsigned int t = u & 0xffff0000u; float f; __builtin_memcpy(&f, &t, 4); return f;
}

// ---------------- edge dtype detection (int32 vs raw int64) ----------------
__global__ void detect_k(const int* __restrict__ ei, int* __restrict__ flag) {
    __shared__ int bad;
    if (threadIdx.x == 0) bad = 0;
    __syncthreads();
    const long long* e64 = (const long long*)ei;
    long long v = e64[threadIdx.x];
    long long w = e64[300000 + threadIdx.x];
    if (v < 0 || v >= N_NODES || w < 0 || w >= N_NODES) bad = 1;
    __syncthreads();
    if (threadIdx.x == 0) *flag = (bad == 0) ? 1 : 0;   // 1 => int64 layout
}

__device__ inline int edge_at(const int* __restrict__ ei, int is64, long long idx) {
    long long v = is64 ? ((const long long*)ei)[idx] : (long long)ei[idx];
    if (v < 0) v = 0;
    if (v >= N_NODES) v = N_NODES - 1;
    return (int)v;
}

// ---------------- CSR construction ----------------

__global__ void count_k(const int* __restrict__ ei, const int* __restrict__ flag,
                        int* __restrict__ cnt) {
    int e = blockIdx.x * 256 + threadIdx.x;
    if (e < N_EDGES) {
        int d = edge_at(ei, *flag, (long long)N_EDGES + e);
        atomicAdd(&cnt[d], 1);
    }
}

__global__ void scan_block_k(const int* __restrict__ cnt, int* __restrict__ row_start,
                             int* __restrict__ bsums) {
    __shared__ int sm[256];
    int t = threadIdx.x;
    int i = blockIdx.x * 256 + t;
    int v = (i < N_NODES) ? cnt[i] : 0;
    sm[t] = v; __syncthreads();
    #pragma unroll
    for (int off = 1; off < 256; off <<= 1) {
        int x = (t >= off) ? sm[t - off] : 0;
        __syncthreads();
        sm[t] += x;
        __syncthreads();
    }
    if (i < N_NODES) row_start[i] = sm[t] - v;
    if (t == 255)    bsums[blockIdx.x] = sm[255];
}

__global__ void scan_top_k(int* __restrict__ bsums) {
    __shared__ int sm[256];
    int t = threadIdx.x;
    int v = (t < SCAN_BLOCKS) ? bsums[t] : 0;
    sm[t] = v; __syncthreads();
    #pragma unroll
    for (int off = 1; off < 256; off <<= 1) {
        int x = (t >= off) ? sm[t - off] : 0;
        __syncthreads();
        sm[t] += x;
        __syncthreads();
    }
    if (t < SCAN_BLOCKS) bsums[t] = sm[t] - v;
}

__global__ void finalize_k(const int* __restrict__ cnt, int* __restrict__ row_start,
                           int* __restrict__ cursor, const int* __restrict__ bsums,
                           float* __restrict__ dinv2, float* __restrict__ dinv1) {
    int i = blockIdx.x * 256 + threadIdx.x;
    if (i >= N_NODES) return;
    int rs = row_start[i] + bsums[blockIdx.x];
    row_start[i] = rs;
    cursor[i]    = rs;
    float c = (float)cnt[i];
    dinv2[i] = rsqrtf(c + 3.0f);   // fill=2: cnt + 1 + 2
    dinv1[i] = rsqrtf(c + 2.0f);   // fill=1: cnt + 1 + 1
}

__global__ void fill_k(const int* __restrict__ ei, const int* __restrict__ flag,
                       int* __restrict__ cursor, int* __restrict__ csr) {
    int e = blockIdx.x * 256 + threadIdx.x;
    if (e >= N_EDGES) return;
    int is64 = *flag;
    int s = edge_at(ei, is64, e);
    int d = edge_at(ei, is64, (long long)N_EDGES + e);
    int pos = atomicAdd(&cursor[d], 1);
    csr[pos] = s;
}

// ---------------- x (f32) -> xbf (bf16), whole array ----------------
__global__ void cvt_x_k(const float* __restrict__ x, unsigned short* __restrict__ xbf) {
    int t = blockIdx.x * 256 + threadIdx.x;     // 1.6M threads, 4 elems each
    float4 v = *(const float4*)(x + (size_t)t * 4);
    unsigned int lo = ((unsigned int)f2bf(v.y) << 16) | (unsigned int)f2bf(v.x);
    unsigned int hi = ((unsigned int)f2bf(v.w) << 16) | (unsigned int)f2bf(v.z);
    uint2 r; r.x = lo; r.y = hi;
    *(uint2*)(xbf + (size_t)t * 4) = r;
}

// ---------------- W (f32 [k][n]) -> Wt (bf16 [mat][n][k]) ----------------
__global__ void transpose_k(const float* __restrict__ W1,
                            const float* __restrict__ W2,
                            const float* __restrict__ W3,
                            unsigned short* __restrict__ Wt) {
    int t = blockIdx.x * 256 + threadIdx.x;     // 0..49151
    int mat = t >> 14;
    int o = t & 16383;
    int n = o >> 7, k = o & 127;
    const float* W = (mat == 0) ? W1 : ((mat == 1) ? W2 : W3);
    Wt[t] = f2bf(W[k * 128 + n]);
}

// ------- Aggregation (bf16 rows, f32 accum), unroll-4 for memory-level parallelism
// agg[d] = di[d]*sum_s(di[s]*h[s]) + di[d]^2*(1+fill)*h[d]

__global__ __launch_bounds__(256) void agg_k(
        const unsigned short* __restrict__ h, unsigned short* __restrict__ out,
        const int* __restrict__ row_start, const int* __restrict__ cnt,
        const int* __restrict__ csr, const float* __restrict__ dinv, float fillp1) {
    int lane = threadIdx.x & 63;
    int node = blockIdx.x * 4 + (threadIdx.x >> 6);      // 12500 blocks exact
    float di = dinv[node];
    int rs = row_start[node];
    int c  = cnt[node];
    const unsigned int* hp = (const unsigned int*)h + lane;  // uint stride 64/row... no:
    // row stride in uints = 64; lane covers channels 2*lane,2*lane+1 at uint idx lane.
    float p0 = 0.f, p1 = 0.f, q0 = 0.f, q1 = 0.f;
    float r0 = 0.f, r1 = 0.f, s0 = 0.f, s1 = 0.f;
    int i = 0;
    for (; i + 4 <= c; i += 4) {
        int e0 = csr[rs + i], e1 = csr[rs + i + 1];
        int e2 = csr[rs + i + 2], e3 = csr[rs + i + 3];
        float w0 = dinv[e0], w1 = dinv[e1], w2 = dinv[e2], w3 = dinv[e3];
        unsigned int u0 = hp[(size_t)e0 * 64];
        unsigned int u1 = hp[(size_t)e1 * 64];
        unsigned int u2 = hp[(size_t)e2 * 64];
        unsigned int u3 = hp[(size_t)e3 * 64];
        p0 = fmaf(w0, bf_lo(u0), p0); p1 = fmaf(w0, bf_hi(u0), p1);
        q0 = fmaf(w1, bf_lo(u1), q0); q1 = fmaf(w1, bf_hi(u1), q1);
        r0 = fmaf(w2, bf_lo(u2), r0); r1 = fmaf(w2, bf_hi(u2), r1);
        s0 = fmaf(w3, bf_lo(u3), s0); s1 = fmaf(w3, bf_hi(u3), s1);
    }
    for (; i < c; i++) {
        int e = csr[rs + i];
        float w = dinv[e];
        unsigned int u = hp[(size_t)e * 64];
        p0 = fmaf(w, bf_lo(u), p0); p1 = fmaf(w, bf_hi(u), p1);
    }
    float a0 = (p0 + q0) + (r0 + s0);
    float a1 = (p1 + q1) + (r1 + s1);
    unsigned int us = hp[(size_t)node * 64];
    float dd = di * di * fillp1;
    a0 = di * a0 + dd * bf_lo(us);
    a1 = di * a1 + dd * bf_hi(us);
    unsigned int res = ((unsigned int)f2bf(a1) << 16) | (unsigned int)f2bf(a0);
    *((unsigned int*)out + (size_t)node * 64 + lane) = res;
}

// ---------------- MFMA GEMM (16x16x32 bf16) + fused epilogue ----------------
// Wave = 16 rows x 128 cols. A layout: A[m=lane&15][k=quad*8+j]; C/D:
// col=lane&15, row=quad*4+reg  [measured m89/m91].
// MODE 0: out_bf = relu(LN(A@W + bias)*gamma + beta)     (bf16 out)
// MODE 1: out_f  = A@W + bias + resid                    (f32 out)

template<int MODE>
__global__ __launch_bounds__(256) void gemm_k(
        const unsigned short* __restrict__ A,      // bf16 [N][128]
        const unsigned short* __restrict__ Wt,     // bf16 [n][k] 128x128
        const float* __restrict__ bias,
        const float* __restrict__ gamma,
        const float* __restrict__ beta,
        const float* __restrict__ resid,           // f32 (MODE 1)
        unsigned short* __restrict__ out_bf,       // MODE 0
        float* __restrict__ out_f) {               // MODE 1
    int lane = threadIdx.x & 63;
    int wv   = threadIdx.x >> 6;
    int r0   = (blockIdx.x * 4 + wv) * 16;
    int m = lane & 15, q = lane >> 4;

    int arow = r0 + m; if (arow >= N_NODES) arow = N_NODES - 1;  // clamp load; mask store
    const unsigned short* ap = A + (size_t)arow * DCH + q * 8;
    bf16x8 afr[4];
    #pragma unroll
    for (int kt = 0; kt < 4; kt++) afr[kt] = *(const bf16x8*)(ap + kt * 32);

    f32x4 acc[8];
    #pragma unroll
    for (int nt = 0; nt < 8; nt++) {
        f32x4 cacc = {0.f, 0.f, 0.f, 0.f};
        const unsigned short* bp = Wt + (size_t)(nt * 16 + m) * DCH + q * 8;
        #pragma unroll
        for (int kt = 0; kt < 4; kt++) {
            bf16x8 bfr = *(const bf16x8*)(bp + kt * 32);
            cacc = __builtin_amdgcn_mfma_f32_16x16x32_bf16(afr[kt], bfr, cacc, 0, 0, 0);
        }
        acc[nt] = cacc;
    }

    float bv[8];
    #pragma unroll
    for (int nt = 0; nt < 8; nt++) bv[nt] = bias[nt * 16 + m];

    if (MODE == 0) {
        float gv[8], bev[8];
        #pragma unroll
        for (int nt = 0; nt < 8; nt++) { gv[nt] = gamma[nt*16+m]; bev[nt] = beta[nt*16+m]; }
        #pragma unroll
        for (int nt = 0; nt < 8; nt++)
            #pragma unroll
            for (int r = 0; r < 4; r++) acc[nt][r] += bv[nt];
        #pragma unroll
        for (int r = 0; r < 4; r++) {
            float s = 0.f, qs = 0.f;
            #pragma unroll
            for (int nt = 0; nt < 8; nt++) { float v = acc[nt][r]; s += v; qs += v * v; }
            #pragma unroll
            for (int msk = 1; msk < 16; msk <<= 1) {
                s  += __shfl_xor(s,  msk, 16);
                qs += __shfl_xor(qs, msk, 16);
            }
            float mean = s * (1.f / 128.f);
            float var  = fmaxf(qs * (1.f / 128.f) - mean * mean, 0.f);
            float rstd = rsqrtf(var + LN_EPS);
            int row = r0 + q * 4 + r;
            if (row < N_NODES) {
                #pragma unroll
                for (int nt = 0; nt < 8; nt++) {
                    float v = (acc[nt][r] - mean) * rstd * gv[nt] + bev[nt];
                    out_bf[(size_t)row * DCH + nt * 16 + m] = f2bf(fmaxf(v, 0.f));
                }
            }
        }
    } else {
        #pragma unroll
        for (int r = 0; r < 4; r++) {
            int row = r0 + q * 4 + r;
            if (row < N_NODES) {
                #pragma unroll
                for (int nt = 0; nt < 8; nt++) {
                    float v = acc[nt][r] + bv[nt]
                            + resid[(size_t)row * DCH + nt * 16 + m];
                    out_f[(size_t)row * DCH + nt * 16 + m] = v;
                }
            }
        }
    }
}

// ---------------- launcher ----------------

extern "C" void kernel_launch(void* const* d_in, const int* in_sizes, int n_in,
                              void* d_out, int out_size, void* d_ws, size_t ws_size,
                              hipStream_t stream) {
    const float* x   = (const float*)d_in[0];
    const int*   ei  = (const int*)d_in[1];
    const float* W1  = (const float*)d_in[2];
    const float* b1  = (const float*)d_in[3];
    const float* g1  = (const float*)d_in[4];
    const float* be1 = (const float*)d_in[5];
    const float* W2  = (const float*)d_in[6];
    const float* b2  = (const float*)d_in[7];
    const float* g2  = (const float*)d_in[8];
    const float* be2 = (const float*)d_in[9];
    const float* W3  = (const float*)d_in[10];
    const float* b3  = (const float*)d_in[11];
    float* out = (float*)d_out;

    char* p = (char*)d_ws;
    auto alloc = [&](size_t bytes) -> void* {
        void* r = (void*)p; p += (bytes + 255) & ~(size_t)255; return r;
    };
    int*   eflag     = (int*)  alloc(256);
    int*   cnt       = (int*)  alloc((size_t)N_NODES * 4);
    int*   row_start = (int*)  alloc((size_t)N_NODES * 4);
    int*   cursor    = (int*)  alloc((size_t)N_NODES * 4);
    int*   bsums     = (int*)  alloc(256 * 4);
    float* dinv2     = (float*)alloc((size_t)N_NODES * 4);
    float* dinv1     = (float*)alloc((size_t)N_NODES * 4);
    int*   csr       = (int*)  alloc((size_t)N_EDGES * 4);
    unsigned short* Wt   = (unsigned short*)alloc((size_t)3 * 128 * 128 * 2);
    unsigned short* aggb = (unsigned short*)alloc((size_t)N_NODES * DCH * 2);
    // d_out (25.6 MB f32) hosts two bf16 buffers (12.8 MB each):
    //   [0 .. 12.8M)  = hbuf (inter-layer activations, bf16)
    //   [12.8 .. 25.6) = xbf  (bf16 copy of x; only needed by agg layer 1)
    // Layer-3 gemm reads aggb(ws)+x(d_in) and writes the full f32 d_out last.
    unsigned short* hbuf = (unsigned short*)d_out;
    unsigned short* xbf  = hbuf + (size_t)N_NODES * DCH;

    hipMemsetAsync(cnt, 0, (size_t)N_NODES * 4, stream);
    detect_k<<<1, 256, 0, stream>>>(ei, eflag);
    count_k<<<(N_EDGES + 255) / 256, 256, 0, stream>>>(ei, eflag, cnt);
    scan_block_k<<<SCAN_BLOCKS, 256, 0, stream>>>(cnt, row_start, bsums);
    scan_top_k<<<1, 256, 0, stream>>>(bsums);
    finalize_k<<<SCAN_BLOCKS, 256, 0, stream>>>(cnt, row_start, cursor, bsums, dinv2, dinv1);
    fill_k<<<(N_EDGES + 255) / 256, 256, 0, stream>>>(ei, eflag, cursor, csr);
    cvt_x_k<<<(N_NODES * DCH / 4) / 256, 256, 0, stream>>>(x, xbf);   // 6250 blocks
    transpose_k<<<192, 256, 0, stream>>>(W1, W2, W3, Wt);

    const int G_BLOCKS = (N_NODES + 63) / 64;   // 782

    // layer 1
    agg_k<<<N_NODES / 4, 256, 0, stream>>>(xbf, aggb, row_start, cnt, csr, dinv2, 3.0f);
    gemm_k<0><<<G_BLOCKS, 256, 0, stream>>>(aggb, Wt, b1, g1, be1, nullptr, hbuf, nullptr);
    // layer 2
    agg_k<<<N_NODES / 4, 256, 0, stream>>>(hbuf, aggb, row_start, cnt, csr, dinv2, 3.0f);
    gemm_k<0><<<G_BLOCKS, 256, 0, stream>>>(aggb, Wt + 16384, b2, g2, be2, nullptr, hbuf, nullptr);
    // layer 3: fill=1, + b3 + residual x (f32), f32 out
    agg_k<<<N_NODES / 4, 256, 0, stream>>>(hbuf, aggb, row_start, cnt, csr, dinv1, 2.0f);
    gemm_k<1><<<G_BLOCKS, 256, 0, stream>>>(aggb, Wt + 32768, b3, nullptr, nullptr, x, nullptr, out);
}

// Round 6
// 310.514 us; speedup vs baseline: 1.5735x; 1.0960x over previous
//
#include <hip/hip_runtime.h>
#include <hip/hip_bf16.h>
#include <cstdint>

#define N_NODES 50000
#define N_EDGES 600000
#define DCH     128
#define LN_EPS  1e-5f
#define SCAN_BLOCKS 196   // ceil(50000/256)
#define CSR_CAP 1000000   // >= 600000 + 50000*7 (pad-to-8 worst case)

typedef __attribute__((ext_vector_type(8))) __bf16 bf16x8;
typedef __attribute__((ext_vector_type(4))) float  f32x4;

__device__ inline unsigned short f2bf(float f) {
    unsigned int b; __builtin_memcpy(&b, &f, 4);
    b = b + 0x7fffu + ((b >> 16) & 1u);   // round-to-nearest-even
    return (unsigned short)(b >> 16);
}
__device__ inline float bf_lo(unsigned int u) {
    unsigned int t = u << 16; float f; __builtin_memcpy(&f, &t, 4); return f;
}
__device__ inline float bf_hi(unsigned int u) {
    unsigned int t = u & 0xffff0000u; float f; __builtin_memcpy(&f, &t, 4); return f;
}

// ---------------- edge dtype detection (int32 vs raw int64) ----------------
__global__ void detect_k(const int* __restrict__ ei, int* __restrict__ flag) {
    __shared__ int bad;
    if (threadIdx.x == 0) bad = 0;
    __syncthreads();
    const long long* e64 = (const long long*)ei;
    long long v = e64[threadIdx.x];
    long long w = e64[300000 + threadIdx.x];
    if (v < 0 || v >= N_NODES || w < 0 || w >= N_NODES) bad = 1;
    __syncthreads();
    if (threadIdx.x == 0) *flag = (bad == 0) ? 1 : 0;   // 1 => int64 layout
}

__device__ inline int edge_at(const int* __restrict__ ei, int is64, long long idx) {
    long long v = is64 ? ((const long long*)ei)[idx] : (long long)ei[idx];
    if (v < 0) v = 0;
    if (v >= N_NODES) v = N_NODES - 1;
    return (int)v;
}

// ---------------- CSR construction (padded to multiple of 8) ----------------

__global__ void count_k(const int* __restrict__ ei, const int* __restrict__ flag,
                        int* __restrict__ cnt) {
    int e = blockIdx.x * 256 + threadIdx.x;
    if (e < N_EDGES) {
        int d = edge_at(ei, *flag, (long long)N_EDGES + e);
        atomicAdd(&cnt[d], 1);
    }
}

__global__ void scan_block_k(const int* __restrict__ cnt, int* __restrict__ row_start,
                             int* __restrict__ bsums) {
    __shared__ int sm[256];
    int t = threadIdx.x;
    int i = blockIdx.x * 256 + t;
    int v = (i < N_NODES) ? ((cnt[i] + 7) & ~7) : 0;     // padded count
    sm[t] = v; __syncthreads();
    #pragma unroll
    for (int off = 1; off < 256; off <<= 1) {
        int x = (t >= off) ? sm[t - off] : 0;
        __syncthreads();
        sm[t] += x;
        __syncthreads();
    }
    if (i < N_NODES) row_start[i] = sm[t] - v;
    if (t == 255)    bsums[blockIdx.x] = sm[255];
}

__global__ void scan_top_k(int* __restrict__ bsums) {
    __shared__ int sm[256];
    int t = threadIdx.x;
    int v = (t < SCAN_BLOCKS) ? bsums[t] : 0;
    sm[t] = v; __syncthreads();
    #pragma unroll
    for (int off = 1; off < 256; off <<= 1) {
        int x = (t >= off) ? sm[t - off] : 0;
        __syncthreads();
        sm[t] += x;
        __syncthreads();
    }
    if (t < SCAN_BLOCKS) bsums[t] = sm[t] - v;
}

__global__ void finalize_k(const int* __restrict__ cnt, int* __restrict__ row_start,
                           int* __restrict__ cursor, const int* __restrict__ bsums,
                           float* __restrict__ dinv2, float* __restrict__ dinv1) {
    int i = blockIdx.x * 256 + threadIdx.x;
    if (i >= N_NODES) return;
    int rs = row_start[i] + bsums[blockIdx.x];
    row_start[i] = rs;
    cursor[i]    = rs;
    float c = (float)cnt[i];
    dinv2[i] = rsqrtf(c + 3.0f);   // fill=2: cnt + 1 + 2
    dinv1[i] = rsqrtf(c + 2.0f);   // fill=1: cnt + 1 + 1
}

__global__ void pad_fill_k(int* __restrict__ csr) {
    int i = blockIdx.x * 256 + threadIdx.x;
    if (i < CSR_CAP) csr[i] = N_NODES;      // zero-row sentinel
}

__global__ void fill_k(const int* __restrict__ ei, const int* __restrict__ flag,
                       int* __restrict__ cursor, int* __restrict__ csr) {
    int e = blockIdx.x * 256 + threadIdx.x;
    if (e >= N_EDGES) return;
    int is64 = *flag;
    int s = edge_at(ei, is64, e);
    int d = edge_at(ei, is64, (long long)N_EDGES + e);
    int pos = atomicAdd(&cursor[d], 1);
    csr[pos] = s;
}

// ---- x (f32) -> xbf = dinv2*x (bf16), rows 0..N; row N = zeros ----
__global__ void cvt_x_k(const float* __restrict__ x, const float* __restrict__ dinv2,
                        unsigned short* __restrict__ xbf) {
    int idx = blockIdx.x * 256 + threadIdx.x;       // thread = 4 channels of one node
    int node = idx >> 5;
    if (node > N_NODES) return;
    int co = (idx & 31) * 4;
    uint2 r;
    if (node == N_NODES) {
        r.x = 0u; r.y = 0u;
    } else {
        float4 v = *(const float4*)(x + (size_t)node * DCH + co);
        float d = dinv2[node];
        r.x = ((unsigned int)f2bf(v.y * d) << 16) | (unsigned int)f2bf(v.x * d);
        r.y = ((unsigned int)f2bf(v.w * d) << 16) | (unsigned int)f2bf(v.z * d);
    }
    *(uint2*)(xbf + (size_t)node * DCH + co) = r;
}

// ---------------- W (f32 [k][n]) -> Wt (bf16 [mat][n][k]) ----------------
__global__ void transpose_k(const float* __restrict__ W1,
                            const float* __restrict__ W2,
                            const float* __restrict__ W3,
                            unsigned short* __restrict__ Wt) {
    int t = blockIdx.x * 256 + threadIdx.x;     // 0..49151
    int mat = t >> 14;
    int o = t & 16383;
    int n = o >> 7, k = o & 127;
    const float* W = (mat == 0) ? W1 : ((mat == 1) ? W2 : W3);
    Wt[t] = f2bf(W[k * 128 + n]);
}

// ------- Aggregation over pre-scaled rows: agg[d] = di[d]*(sum_adj hs + fillp1*hs[d])
// CSR lists padded to x8 with sentinel row N (all zeros) -> tail-free, 8 streams.

__global__ __launch_bounds__(256) void agg_k(
        const unsigned short* __restrict__ hs, unsigned short* __restrict__ out,
        const int* __restrict__ row_start, const int* __restrict__ cnt,
        const int* __restrict__ csr, const float* __restrict__ dinv, float fillp1) {
    int lane = threadIdx.x & 63;
    int node = blockIdx.x * 4 + (threadIdx.x >> 6);      // 12500 blocks exact
    float di = dinv[node];
    int rs = row_start[node];
    int pc = (cnt[node] + 7) & ~7;
    const unsigned int* hp = (const unsigned int*)hs + lane;  // uint idx `lane` = ch 2l,2l+1
    float a00 = 0.f, a01 = 0.f, a10 = 0.f, a11 = 0.f;
    float a20 = 0.f, a21 = 0.f, a30 = 0.f, a31 = 0.f;
    float a40 = 0.f, a41 = 0.f, a50 = 0.f, a51 = 0.f;
    float a60 = 0.f, a61 = 0.f, a70 = 0.f, a71 = 0.f;
    for (int i = 0; i < pc; i += 8) {
        int e0 = csr[rs+i+0], e1 = csr[rs+i+1], e2 = csr[rs+i+2], e3 = csr[rs+i+3];
        int e4 = csr[rs+i+4], e5 = csr[rs+i+5], e6 = csr[rs+i+6], e7 = csr[rs+i+7];
        unsigned int u0 = hp[(size_t)e0 * 64];
        unsigned int u1 = hp[(size_t)e1 * 64];
        unsigned int u2 = hp[(size_t)e2 * 64];
        unsigned int u3 = hp[(size_t)e3 * 64];
        unsigned int u4 = hp[(size_t)e4 * 64];
        unsigned int u5 = hp[(size_t)e5 * 64];
        unsigned int u6 = hp[(size_t)e6 * 64];
        unsigned int u7 = hp[(size_t)e7 * 64];
        a00 += bf_lo(u0); a01 += bf_hi(u0);
        a10 += bf_lo(u1); a11 += bf_hi(u1);
        a20 += bf_lo(u2); a21 += bf_hi(u2);
        a30 += bf_lo(u3); a31 += bf_hi(u3);
        a40 += bf_lo(u4); a41 += bf_hi(u4);
        a50 += bf_lo(u5); a51 += bf_hi(u5);
        a60 += bf_lo(u6); a61 += bf_hi(u6);
        a70 += bf_lo(u7); a71 += bf_hi(u7);
    }
    float s0 = ((a00 + a10) + (a20 + a30)) + ((a40 + a50) + (a60 + a70));
    float s1 = ((a01 + a11) + (a21 + a31)) + ((a41 + a51) + (a61 + a71));
    unsigned int us = hp[(size_t)node * 64];
    s0 = di * (s0 + fillp1 * bf_lo(us));
    s1 = di * (s1 + fillp1 * bf_hi(us));
    unsigned int res = ((unsigned int)f2bf(s1) << 16) | (unsigned int)f2bf(s0);
    *((unsigned int*)out + (size_t)node * 64 + lane) = res;
}

// ---------------- MFMA GEMM (16x16x32 bf16), 32 rows/wave ----------------
// A layout: A[m=lane&15][k=quad*8+j]; C/D: col=lane&15, row=quad*4+reg.
// MODE 0: out_bf = dnext[row] * relu(LN(A@W + bias)*gamma + beta)   (bf16)
// MODE 1: out_f  = A@W + bias + resid                               (f32)

template<int MODE>
__global__ __launch_bounds__(256) void gemm_k(
        const unsigned short* __restrict__ A,      // bf16 [N][128]
        const unsigned short* __restrict__ Wt,     // bf16 [n][k] 128x128
        const float* __restrict__ bias,
        const float* __restrict__ gamma,
        const float* __restrict__ beta,
        const float* __restrict__ dnext,           // MODE 0 epilogue scale
        const float* __restrict__ resid,           // MODE 1
        unsigned short* __restrict__ out_bf,
        float* __restrict__ out_f) {
    int lane = threadIdx.x & 63;
    int wv   = threadIdx.x >> 6;
    int r0   = (blockIdx.x * 4 + wv) * 32;         // 32 rows per wave
    int m = lane & 15, q = lane >> 4;

    bf16x8 afr[2][4];
    #pragma unroll
    for (int mt = 0; mt < 2; mt++) {
        int arow = r0 + mt * 16 + m; if (arow >= N_NODES) arow = N_NODES - 1;
        const unsigned short* ap = A + (size_t)arow * DCH + q * 8;
        #pragma unroll
        for (int kt = 0; kt < 4; kt++) afr[mt][kt] = *(const bf16x8*)(ap + kt * 32);
    }

    f32x4 acc[2][8];
    #pragma unroll
    for (int nt = 0; nt < 8; nt++) {
        f32x4 c0 = {0.f,0.f,0.f,0.f}, c1 = {0.f,0.f,0.f,0.f};
        const unsigned short* bp = Wt + (size_t)(nt * 16 + m) * DCH + q * 8;
        #pragma unroll
        for (int kt = 0; kt < 4; kt++) {
            bf16x8 bfr = *(const bf16x8*)(bp + kt * 32);
            c0 = __builtin_amdgcn_mfma_f32_16x16x32_bf16(afr[0][kt], bfr, c0, 0, 0, 0);
            c1 = __builtin_amdgcn_mfma_f32_16x16x32_bf16(afr[1][kt], bfr, c1, 0, 0, 0);
        }
        acc[0][nt] = c0; acc[1][nt] = c1;
    }

    float bv[8];
    #pragma unroll
    for (int nt = 0; nt < 8; nt++) bv[nt] = bias[nt * 16 + m];

    if (MODE == 0) {
        float gv[8], bev[8];
        #pragma unroll
        for (int nt = 0; nt < 8; nt++) { gv[nt] = gamma[nt*16+m]; bev[nt] = beta[nt*16+m]; }
        #pragma unroll
        for (int mt = 0; mt < 2; mt++) {
            #pragma unroll
            for (int nt = 0; nt < 8; nt++)
                #pragma unroll
                for (int r = 0; r < 4; r++) acc[mt][nt][r] += bv[nt];
            #pragma unroll
            for (int r = 0; r < 4; r++) {
                float s = 0.f, qs = 0.f;
                #pragma unroll
                for (int nt = 0; nt < 8; nt++) { float v = acc[mt][nt][r]; s += v; qs += v*v; }
                #pragma unroll
                for (int msk = 1; msk < 16; msk <<= 1) {
                    s  += __shfl_xor(s,  msk, 16);
                    qs += __shfl_xor(qs, msk, 16);
                }
                float mean = s * (1.f / 128.f);
                float var  = fmaxf(qs * (1.f / 128.f) - mean * mean, 0.f);
                float rstd = rsqrtf(var + LN_EPS);
                int row = r0 + mt * 16 + q * 4 + r;
                if (row < N_NODES) {
                    float dscale = dnext[row];
                    #pragma unroll
                    for (int nt = 0; nt < 8; nt++) {
                        float v = (acc[mt][nt][r] - mean) * rstd * gv[nt] + bev[nt];
                        v = fmaxf(v, 0.f) * dscale;
                        out_bf[(size_t)row * DCH + nt * 16 + m] = f2bf(v);
                    }
                }
            }
        }
    } else {
        #pragma unroll
        for (int mt = 0; mt < 2; mt++)
            #pragma unroll
            for (int r = 0; r < 4; r++) {
                int row = r0 + mt * 16 + q * 4 + r;
                if (row < N_NODES) {
                    #pragma unroll
                    for (int nt = 0; nt < 8; nt++) {
                        float v = acc[mt][nt][r] + bv[nt]
                                + resid[(size_t)row * DCH + nt * 16 + m];
                        out_f[(size_t)row * DCH + nt * 16 + m] = v;
                    }
                }
            }
    }
}

// ---------------- launcher ----------------

extern "C" void kernel_launch(void* const* d_in, const int* in_sizes, int n_in,
                              void* d_out, int out_size, void* d_ws, size_t ws_size,
                              hipStream_t stream) {
    const float* x   = (const float*)d_in[0];
    const int*   ei  = (const int*)d_in[1];
    const float* W1  = (const float*)d_in[2];
    const float* b1  = (const float*)d_in[3];
    const float* g1  = (const float*)d_in[4];
    const float* be1 = (const float*)d_in[5];
    const float* W2  = (const float*)d_in[6];
    const float* b2  = (const float*)d_in[7];
    const float* g2  = (const float*)d_in[8];
    const float* be2 = (const float*)d_in[9];
    const float* W3  = (const float*)d_in[10];
    const float* b3  = (const float*)d_in[11];
    float* out = (float*)d_out;

    char* p = (char*)d_ws;
    auto alloc = [&](size_t bytes) -> void* {
        void* r = (void*)p; p += (bytes + 255) & ~(size_t)255; return r;
    };
    int*   eflag     = (int*)  alloc(256);
    int*   cnt       = (int*)  alloc((size_t)N_NODES * 4);
    int*   row_start = (int*)  alloc((size_t)N_NODES * 4);
    int*   cursor    = (int*)  alloc((size_t)N_NODES * 4);
    int*   bsums     = (int*)  alloc(256 * 4);
    float* dinv2     = (float*)alloc((size_t)N_NODES * 4);
    float* dinv1     = (float*)alloc((size_t)N_NODES * 4);
    int*   csr       = (int*)  alloc((size_t)CSR_CAP * 4);
    unsigned short* Wt   = (unsigned short*)alloc((size_t)3 * 128 * 128 * 2);
    unsigned short* aggb = (unsigned short*)alloc((size_t)N_NODES * DCH * 2);
    unsigned short* xbf  = (unsigned short*)alloc((size_t)(N_NODES + 1) * DCH * 2);
    unsigned short* hbuf = (unsigned short*)alloc((size_t)(N_NODES + 1) * DCH * 2);

    hipMemsetAsync(cnt, 0, (size_t)N_NODES * 4, stream);
    hipMemsetAsync(hbuf + (size_t)N_NODES * DCH, 0, DCH * 2, stream);  // zero sentinel row
    detect_k<<<1, 256, 0, stream>>>(ei, eflag);
    count_k<<<(N_EDGES + 255) / 256, 256, 0, stream>>>(ei, eflag, cnt);
    scan_block_k<<<SCAN_BLOCKS, 256, 0, stream>>>(cnt, row_start, bsums);
    scan_top_k<<<1, 256, 0, stream>>>(bsums);
    finalize_k<<<SCAN_BLOCKS, 256, 0, stream>>>(cnt, row_start, cursor, bsums, dinv2, dinv1);
    pad_fill_k<<<(CSR_CAP + 255) / 256, 256, 0, stream>>>(csr);
    fill_k<<<(N_EDGES + 255) / 256, 256, 0, stream>>>(ei, eflag, cursor, csr);
    cvt_x_k<<<((N_NODES + 1) * 32 + 255) / 256, 256, 0, stream>>>(x, dinv2, xbf);
    transpose_k<<<192, 256, 0, stream>>>(W1, W2, W3, Wt);

    const int G_BLOCKS = (N_NODES + 127) / 128;   // 391

    // layer 1: agg(dinv2*x) -> @W1+b1 -> LN,relu, *dinv2 -> hbuf
    agg_k<<<N_NODES / 4, 256, 0, stream>>>(xbf, aggb, row_start, cnt, csr, dinv2, 3.0f);
    gemm_k<0><<<G_BLOCKS, 256, 0, stream>>>(aggb, Wt, b1, g1, be1, dinv2, nullptr, hbuf, nullptr);
    // layer 2: agg(dinv2*h1) -> @W2+b2 -> LN,relu, *dinv1 -> hbuf
    agg_k<<<N_NODES / 4, 256, 0, stream>>>(hbuf, aggb, row_start, cnt, csr, dinv2, 3.0f);
    gemm_k<0><<<G_BLOCKS, 256, 0, stream>>>(aggb, Wt + 16384, b2, g2, be2, dinv1, nullptr, hbuf, nullptr);
    // layer 3: agg(dinv1*h2) -> @W3+b3 + x -> f32 d_out
    agg_k<<<N_NODES / 4, 256, 0, stream>>>(hbuf, aggb, row_start, cnt, csr, dinv1, 2.0f);
    gemm_k<1><<<G_BLOCKS, 256, 0, stream>>>(aggb, Wt + 32768, b3, nullptr, nullptr, nullptr, x, nullptr, out);
}